// Round 4
// baseline (638.804 us; speedup 1.0000x reference)
//
#include <hip/hip_runtime.h>
#include <stdint.h>

// SparseConv2D as DENSE f16 MFMA GEMM: out[f,hw] = relu(W[f,:] @ X[:,hw] + b[f]).
// R9: R7/R8 failed the container twice; only structural param never proven in
// this harness was the 128KiB double-buffer LDS. R9 keeps the R7 theory fixes
// (acc 32 regs/thread, reg-held cross-strip prefetch, fragment-packed W) on a
// SINGLE 64KiB LDS buffer (R5/R6-proven) + __launch_bounds__(1024,8) (R5's).
// Schedule per block (2 strips): stage(s0) -> bar -> [prefetch s1 -> hold[32]
// interleaved with s0 MFMAs] -> epilogue(s0) -> bar -> hold->LDS (4 ds_write)
// -> bar -> s1 MFMAs -> epilogue(s1). Keeps R6's XOR slot-swizzle (0 conflicts
// measured) and the m89-verified C/D mapping.

#define NF 512
#define NC 512
#define HW 65536
#define BN 64  // hw columns per strip

typedef _Float16 f16x8 __attribute__((ext_vector_type(8)));
typedef float f32x4 __attribute__((ext_vector_type(4)));

// prep: masked fp32 W -> fragment-linear f16.
// wpk[((t*16+ks)*64+lane)*8 + j] = W[t*16+(lane&15)][ks*32+(lane>>4)*8+j]
__global__ __launch_bounds__(256) void prep_w(const float* __restrict__ kern,
                                              _Float16* __restrict__ wpk) {
  const int idx = blockIdx.x * 256 + threadIdx.x;  // 0..32767
  const int lane = idx & 63;
  const int ks = (idx >> 6) & 15;
  const int t = idx >> 10;
  const int row = t * 16 + (lane & 15);
  const int col = ks * 32 + (lane >> 4) * 8;
  const float4 v0 = *(const float4*)(kern + (size_t)row * NC + col);
  const float4 v1 = *(const float4*)(kern + (size_t)row * NC + col + 4);
  f16x8 o;
  o[0] = (_Float16)v0.x; o[1] = (_Float16)v0.y;
  o[2] = (_Float16)v0.z; o[3] = (_Float16)v0.w;
  o[4] = (_Float16)v1.x; o[5] = (_Float16)v1.y;
  o[6] = (_Float16)v1.z; o[7] = (_Float16)v1.w;
  *(f16x8*)(wpk + (size_t)idx * 8) = o;
}

__device__ __forceinline__ void compute_half(const _Float16* __restrict__ ap,
                                             const _Float16* __restrict__ bufp,
                                             int bb0, int bb1, int bx0, int bx1,
                                             int l4, int ks0, f32x4 acc[4][2]) {
#pragma unroll
  for (int kk = 0; kk < 8; ++kk) {
    const int ks = ks0 + kk;
    f16x8 a[4], b[2];
#pragma unroll
    for (int mt = 0; mt < 4; ++mt)
      a[mt] = *(const f16x8*)(ap + mt * 8192 + ks * 512);
    b[0] = *(const f16x8*)((const char*)bufp + bb0 + (((ks * 4 + l4) ^ bx0) << 4));
    b[1] = *(const f16x8*)((const char*)bufp + bb1 + (((ks * 4 + l4) ^ bx1) << 4));
#pragma unroll
    for (int nt = 0; nt < 2; ++nt)
#pragma unroll
      for (int mt = 0; mt < 4; ++mt)
        acc[mt][nt] = __builtin_amdgcn_mfma_f32_16x16x32_f16(a[mt], b[nt],
                                                             acc[mt][nt], 0, 0, 0);
  }
}

__device__ __forceinline__ void epilogue(const f32x4 acc[4][2],
                                         const float* __restrict__ bias,
                                         float* __restrict__ out, int f0,
                                         int col0) {
#pragma unroll
  for (int mt = 0; mt < 4; ++mt) {
#pragma unroll
    for (int r = 0; r < 4; ++r) {
      const int f = f0 + mt * 16 + r;  // f0 = wm*64 + l4*4
      const float bv = bias[f];
      float* op = out + (size_t)f * HW + col0;
      op[0] = fmaxf(acc[mt][0][r] + bv, 0.f);
      op[16] = fmaxf(acc[mt][1][r] + bv, 0.f);
    }
  }
}

__global__ __launch_bounds__(1024, 8) void spmm_mfma(
    const float* __restrict__ X, const _Float16* __restrict__ Wpk,
    const float* __restrict__ bias, float* __restrict__ out) {
  __shared__ __align__(16) _Float16 xt[BN * NC];  // 64 KiB, single buffer

  const int tid = threadIdx.x;
  const int wave = tid >> 6;  // 0..15
  const int lane = tid & 63;
  const int ln = lane & 15, l4 = lane >> 4;
  const int wm = wave & 7, wn = wave >> 3;
  const int hwb = blockIdx.x * (2 * BN);
  const int xr = lane & 31;

  // B addressing: row n in [wn*32, wn*32+32), two 16-col tiles
  const int n0 = wn * 32 + ln;
  const int bb0 = n0 * (NC * 2);
  const int bb1 = (n0 + 16) * (NC * 2);
  const int bx0 = n0 & 31;
  const int bx1 = (n0 + 16) & 31;

  // A base: wave wm covers m16-tiles [wm*4, wm*4+4)
  const _Float16* ap = Wpk + (size_t)wm * 32768 + (size_t)lane * 8;

  // ---- stage strip 0: lane owns row n=lane, wave owns c [wave*32,+32) ----
  {
    const float* xp = X + hwb + lane;
    char* rowb = (char*)xt + lane * (NC * 2);
#pragma unroll
    for (int j = 0; j < 4; ++j) {
      const int c0 = wave * 32 + j * 8;
      f16x8 p;
#pragma unroll
      for (int u = 0; u < 8; ++u) p[u] = (_Float16)xp[(size_t)(c0 + u) * HW];
      *(f16x8*)(rowb + ((((c0 >> 3) ^ xr)) << 4)) = p;
    }
  }
  __syncthreads();

  f32x4 acc[4][2] = {};

  // ---- strip 0 compute, with strip-1 prefetch held in 32 regs ----
  const float* xp1 = X + hwb + BN + lane;
  float hold[32];
#pragma unroll
  for (int u = 0; u < 16; ++u) hold[u] = xp1[(size_t)(wave * 32 + u) * HW];

  compute_half(ap, xt, bb0, bb1, bx0, bx1, l4, 0, acc);

#pragma unroll
  for (int u = 16; u < 32; ++u) hold[u] = xp1[(size_t)(wave * 32 + u) * HW];

  compute_half(ap, xt, bb0, bb1, bx0, bx1, l4, 8, acc);

  // strip-0 stores (fire-and-forget) before the barrier
  epilogue(acc, bias, out, wm * 64 + l4 * 4, hwb + wn * 32 + ln);

  __syncthreads();  // all waves done READING xt for strip 0

  // ---- write held strip 1 into xt (4 ds_write_b128) ----
  {
    char* rowb = (char*)xt + lane * (NC * 2);
#pragma unroll
    for (int j = 0; j < 4; ++j) {
      const int c0 = wave * 32 + j * 8;
      f16x8 p;
#pragma unroll
      for (int u = 0; u < 8; ++u) p[u] = (_Float16)hold[j * 8 + u];
      *(f16x8*)(rowb + ((((c0 >> 3) ^ xr)) << 4)) = p;
    }
  }
  __syncthreads();

  // ---- strip 1 ----
#pragma unroll
  for (int mt = 0; mt < 4; ++mt)
#pragma unroll
    for (int nt = 0; nt < 2; ++nt) acc[mt][nt] = (f32x4){0.f, 0.f, 0.f, 0.f};

  compute_half(ap, xt, bb0, bb1, bx0, bx1, l4, 0, acc);
  compute_half(ap, xt, bb0, bb1, bx0, bx1, l4, 8, acc);
  epilogue(acc, bias, out, wm * 64 + l4 * 4, hwb + BN + wn * 32 + ln);
}

extern "C" void kernel_launch(void* const* d_in, const int* in_sizes, int n_in,
                              void* d_out, int out_size, void* d_ws, size_t ws_size,
                              hipStream_t stream) {
  const float* X = (const float*)d_in[0];     // (1, 512, 256, 256) fp32
  const float* kern = (const float*)d_in[1];  // (512, 512) fp32, pre-masked
  // d_in[2] = mask: redundant (kernel already zeroed where mask false)
  const float* bias = (const float*)d_in[3];  // (512,) fp32
  float* out = (float*)d_out;

  _Float16* wpk = (_Float16*)d_ws;  // 512 KB fragment-packed f16 W

  prep_w<<<NF * NC / 8 / 256, 256, 0, stream>>>(kern, wpk);
  spmm_mfma<<<HW / (2 * BN), 1024, 0, stream>>>(X, wpk, bias, out);
}

// Round 6
// 348.126 us; speedup vs baseline: 1.8350x; 1.8350x over previous
//
#include <hip/hip_runtime.h>
#include <stdint.h>

// SparseConv2D as DENSE f16 MFMA GEMM: out[f,hw] = relu(W[f,:] @ X[:,hw] + b[f]).
// R11: every 1024-thread variant at the 128-VGPR boundary has failed the
// container (R7/R8/R10, 6 fails); R6 (512thr,(512,4),64KiB) and R9 ran. So:
// R9's pipeline schedule re-expressed in R6's proven envelope.
//  - 512 threads, 8 waves, __launch_bounds__(512,4), 2 blocks/CU.
//  - strip = 32 hw cols; wave tile 64Mx32N -> acc 32 regs/thread (R7 fix,
//    validated by R9's spill post-mortem: reg budget governs this family).
//  - LDS 2x32KiB double buffer (64KiB total = R6's proven footprint).
//  - T14 prefetch: strip-1 loads -> hold[16] twice, interleaved with strip-0
//    MFMA halves; writes go to buf1 pre-barrier (nobody reads buf1 yet).
//  - fragment-packed W (1KiB contiguous wave A-loads from L2), R6 XOR
//    slot-swizzle (measured 0 conflicts), m89-verified C/D mapping.

#define NF 512
#define NC 512
#define HW 65536
#define SN 32  // hw columns per strip; block covers 2 strips = 64

typedef _Float16 f16x8 __attribute__((ext_vector_type(8)));
typedef float f32x4 __attribute__((ext_vector_type(4)));

// prep: masked fp32 W -> fragment-linear f16.
// wpk[((t*16+ks)*64+lane)*8 + j] = W[t*16+(lane&15)][ks*32+(lane>>4)*8+j]
__global__ __launch_bounds__(256) void prep_w(const float* __restrict__ kern,
                                              _Float16* __restrict__ wpk) {
  const int idx = blockIdx.x * 256 + threadIdx.x;  // 0..32767
  const int lane = idx & 63;
  const int ks = (idx >> 6) & 15;
  const int t = idx >> 10;
  const int row = t * 16 + (lane & 15);
  const int col = ks * 32 + (lane >> 4) * 8;
  const float4 v0 = *(const float4*)(kern + (size_t)row * NC + col);
  const float4 v1 = *(const float4*)(kern + (size_t)row * NC + col + 4);
  f16x8 o;
  o[0] = (_Float16)v0.x; o[1] = (_Float16)v0.y;
  o[2] = (_Float16)v0.z; o[3] = (_Float16)v0.w;
  o[4] = (_Float16)v1.x; o[5] = (_Float16)v1.y;
  o[6] = (_Float16)v1.z; o[7] = (_Float16)v1.w;
  *(f16x8*)(wpk + (size_t)idx * 8) = o;
}

__device__ __forceinline__ void compute_half(const _Float16* __restrict__ ap,
                                             const _Float16* __restrict__ bufp,
                                             int bb0, int bb1, int bx0, int bx1,
                                             int l4, int ks0, f32x4 acc[4][2]) {
#pragma unroll
  for (int kk = 0; kk < 8; ++kk) {
    const int ks = ks0 + kk;
    f16x8 a[4], b[2];
#pragma unroll
    for (int mt = 0; mt < 4; ++mt)
      a[mt] = *(const f16x8*)(ap + mt * 8192 + ks * 512);
    b[0] = *(const f16x8*)((const char*)bufp + bb0 + (((ks * 4 + l4) ^ bx0) << 4));
    b[1] = *(const f16x8*)((const char*)bufp + bb1 + (((ks * 4 + l4) ^ bx1) << 4));
#pragma unroll
    for (int nt = 0; nt < 2; ++nt)
#pragma unroll
      for (int mt = 0; mt < 4; ++mt)
        acc[mt][nt] = __builtin_amdgcn_mfma_f32_16x16x32_f16(a[mt], b[nt],
                                                             acc[mt][nt], 0, 0, 0);
  }
}

__device__ __forceinline__ void epilogue(const f32x4 acc[4][2],
                                         const float* __restrict__ bias,
                                         float* __restrict__ out, int f0,
                                         int col0) {
#pragma unroll
  for (int mt = 0; mt < 4; ++mt) {
#pragma unroll
    for (int r = 0; r < 4; ++r) {
      const int f = f0 + mt * 16 + r;  // f0 = wave*64 + l4*4
      const float bv = bias[f];
      float* op = out + (size_t)f * HW + col0;
      op[0] = fmaxf(acc[mt][0][r] + bv, 0.f);   // nt=0: n = ln
      op[16] = fmaxf(acc[mt][1][r] + bv, 0.f);  // nt=1: n = 16+ln
    }
  }
}

__global__ __launch_bounds__(512, 4) void spmm_mfma(
    const float* __restrict__ X, const _Float16* __restrict__ Wpk,
    const float* __restrict__ bias, float* __restrict__ out) {
  __shared__ __align__(16) _Float16 xt[2][SN * NC];  // 2 x 32 KiB

  const int tid = threadIdx.x;
  const int wave = tid >> 6;  // 0..7: m-range [wave*64, wave*64+64)
  const int lane = tid & 63;
  const int ln = lane & 15, l4 = lane >> 4;
  const int hwb = blockIdx.x * (2 * SN);

  // staging ownership: row n = tid&31, c-range [(tid>>5)*32, +32)
  const int sn = tid & 31;
  const int sc = (tid >> 5) * 32;
  const float* xp0 = X + hwb + sn;
  char* row0 = (char*)&xt[0][0] + sn * (NC * 2);
  char* row1 = (char*)&xt[1][0] + sn * (NC * 2);

  // B addressing: rows n = ln and 16+ln of the 32-row strip
  const int bb0 = ln * (NC * 2);
  const int bb1 = (16 + ln) * (NC * 2);
  const int bx0 = ln;
  const int bx1 = 16 + ln;

  // A base: wave covers m16-tiles [wave*4, wave*4+4)
  const _Float16* ap = Wpk + (size_t)wave * 32768 + (size_t)lane * 8;

  // ---- stage strip 0 into buf0 ----
#pragma unroll
  for (int j = 0; j < 4; ++j) {
    const int c0 = sc + j * 8;
    f16x8 p;
#pragma unroll
    for (int u = 0; u < 8; ++u) p[u] = (_Float16)xp0[(size_t)(c0 + u) * HW];
    *(f16x8*)(row0 + ((((c0 >> 3) ^ sn)) << 4)) = p;
  }
  __syncthreads();

  f32x4 acc[4][2] = {};

  // ---- strip 0 compute, strip-1 prefetch via hold[16] x2 (T14) ----
  const float* xp1 = xp0 + SN;
  float hold[16];
#pragma unroll
  for (int u = 0; u < 16; ++u) hold[u] = xp1[(size_t)(sc + u) * HW];

  compute_half(ap, &xt[0][0], bb0, bb1, bx0, bx1, l4, 0, acc);

  // chunk0 -> buf1 (no barrier: buf1 unread until after syncthreads below)
#pragma unroll
  for (int j = 0; j < 2; ++j) {
    const int c0 = sc + j * 8;
    f16x8 p;
#pragma unroll
    for (int u = 0; u < 8; ++u) p[u] = (_Float16)hold[j * 8 + u];
    *(f16x8*)(row1 + ((((c0 >> 3) ^ sn)) << 4)) = p;
  }
#pragma unroll
  for (int u = 0; u < 16; ++u) hold[u] = xp1[(size_t)(sc + 16 + u) * HW];

  compute_half(ap, &xt[0][0], bb0, bb1, bx0, bx1, l4, 8, acc);

  // strip-0 stores (fire-and-forget) before the barrier
  epilogue(acc, bias, out, wave * 64 + l4 * 4, hwb + ln);

  // chunk1 -> buf1
#pragma unroll
  for (int j = 0; j < 2; ++j) {
    const int c0 = sc + 16 + j * 8;
    f16x8 p;
#pragma unroll
    for (int u = 0; u < 8; ++u) p[u] = (_Float16)hold[j * 8 + u];
    *(f16x8*)(row1 + ((((c0 >> 3) ^ sn)) << 4)) = p;
  }
  __syncthreads();

  // ---- strip 1 ----
#pragma unroll
  for (int mt = 0; mt < 4; ++mt)
#pragma unroll
    for (int nt = 0; nt < 2; ++nt) acc[mt][nt] = (f32x4){0.f, 0.f, 0.f, 0.f};

  compute_half(ap, &xt[1][0], bb0, bb1, bx0, bx1, l4, 0, acc);
  compute_half(ap, &xt[1][0], bb0, bb1, bx0, bx1, l4, 8, acc);
  epilogue(acc, bias, out, wave * 64 + l4 * 4, hwb + SN + ln);
}

extern "C" void kernel_launch(void* const* d_in, const int* in_sizes, int n_in,
                              void* d_out, int out_size, void* d_ws, size_t ws_size,
                              hipStream_t stream) {
  const float* X = (const float*)d_in[0];     // (1, 512, 256, 256) fp32
  const float* kern = (const float*)d_in[1];  // (512, 512) fp32, pre-masked
  // d_in[2] = mask: redundant (kernel already zeroed where mask false)
  const float* bias = (const float*)d_in[3];  // (512,) fp32
  float* out = (float*)d_out;

  _Float16* wpk = (_Float16*)d_ws;  // 512 KB fragment-packed f16 W

  prep_w<<<NF * NC / 8 / 256, 256, 0, stream>>>(kern, wpk);
  spmm_mfma<<<HW / (2 * SN), 512, 0, stream>>>(X, wpk, bias, out);
}